// Round 6
// baseline (10102.309 us; speedup 1.0000x reference)
//
#include <hip/hip_runtime.h>
#include <hip/hip_fp16.h>

#define BB 64
#define SS 512
#define DD 1024
#define HH 1024
#define TICKS 515
#define NBLK 128

typedef _Float16 f16;
typedef unsigned long long u64;
typedef __attribute__((ext_vector_type(8))) _Float16 f16x8;
typedef __attribute__((ext_vector_type(4))) _Float16 f16x4;
typedef __attribute__((ext_vector_type(4))) float f32x4;

struct GruWS {
  unsigned cnt[4 * 8 * 64];    // exact per-(role,tick) ring: slot[r][t&7] at cnt[(r*8+j)*64], 256B apart
  f16 gi0[4][3 * HH][BB];      // [slot][3H][B]
  f16 gi1[4][3 * HH][BB];
  f16 h0b[4][BB][HH];          // [slot][B][H], slot = s & 3
  f16 h1b[4][BB][HH];
};

// ---- MALL-resident communication primitives ----
// Loads: sc0 sc1 (bypass L1/L2, served by MALL).
__device__ __forceinline__ f16x8 ld_sys_16B(const void* p) {
  f16x8 r;
  asm volatile("global_load_dwordx4 %0, %1, off sc0 sc1" : "=v"(r) : "v"(p) : "memory");
  return r;
}
// Stores: atomic swaps with sc1 execute AT the MALL and keep the line resident
// there (plain sc1 stores write through to HBM and the next read misses MALL).
__device__ __forceinline__ void st_mall_16B(void* p, f16x8 v) {
  union { f16x8 v; u64 q[2]; } u; u.v = v;
  asm volatile("global_atomic_swap_x2 %0, %1, off sc1" :: "v"((u64*)p), "v"(u.q[0]) : "memory");
  asm volatile("global_atomic_swap_x2 %0, %1, off sc1" :: "v"((u64*)p + 1), "v"(u.q[1]) : "memory");
}
__device__ __forceinline__ void st_mall_8B(void* p, u64 q) {
  asm volatile("global_atomic_swap_x2 %0, %1, off sc1" :: "v"((u64*)p), "v"(q) : "memory");
}
__device__ __forceinline__ void drain_vm() {
  asm volatile("s_waitcnt vmcnt(0)" ::: "memory");
  __builtin_amdgcn_sched_barrier(0);
}
__device__ __forceinline__ f16x4 ld_sys_f16x4(const f16* p) {
  u64 q = __hip_atomic_load((const u64*)p, __ATOMIC_RELAXED, __HIP_MEMORY_SCOPE_SYSTEM);
  union { u64 q; f16x4 v; } u; u.q = q; return u.v;
}
__device__ __forceinline__ float ld_sys_f16s(const f16* p) {
  unsigned short s = __hip_atomic_load((const unsigned short*)p, __ATOMIC_RELAXED, __HIP_MEMORY_SCOPE_SYSTEM);
  union { unsigned short s; f16 h; } u; u.s = s; return (float)u.h;
}

// done(role, tick): ALL 32 blocks of `role` completed `tick`. Monotone ring slot.
// Called by up to 3 lanes of wave 0 with different args -> divergent loop polls
// all dependencies in parallel (one vector load per iteration).
__device__ __forceinline__ void wait_done(unsigned* cnt, int role, int tick) {
  if (tick < 0) return;
  unsigned* c = &cnt[(role * 8 + (tick & 7)) * 64];
  const unsigned tgt = 32u * ((unsigned)tick / 8u + 1u);
  while (__hip_atomic_load(c, __ATOMIC_RELAXED, __HIP_MEMORY_SCOPE_SYSTEM) < tgt)
    __builtin_amdgcn_s_sleep(2);
  asm volatile("" ::: "memory");
}

__global__ void gru_init(const float* __restrict__ h0, GruWS* __restrict__ ws) {
  int i = blockIdx.x * 256 + threadIdx.x;
  // pack 4 consecutive f16 and atomic-swap 8B so the lines are MALL-resident
  int j = i * 4;
  if (j < 2 * BB * HH) {
    union { f16 h[4]; u64 q; } u;
#pragma unroll
    for (int k = 0; k < 4; ++k) u.h[k] = (f16)h0[j + k];
    if (j < BB * HH) st_mall_8B(&ws->h0b[3][0][j], u.q);            // slot 3 == state of step -1
    else             st_mall_8B(&ws->h1b[3][0][j - BB * HH], u.q);
  }
  if (i < 4 * 8) {
    __hip_atomic_store(&ws->cnt[i * 64], 0u, __ATOMIC_RELAXED, __HIP_MEMORY_SCOPE_SYSTEM);
  }
}

// One K-pass (this wave's K-quarter, one nt column-half): 96 MFMA + LDS K-reduce.
__device__ __forceinline__ void mma_pass(const f16x8 areg[8][4], const f16x8* bnt,
                                         float* red, int lane, int wave, f32x4 acc[3]) {
  f32x4 pacc[4][3];
#pragma unroll
  for (int m = 0; m < 4; ++m)
#pragma unroll
    for (int g = 0; g < 3; ++g) pacc[m][g] = (f32x4){0.f, 0.f, 0.f, 0.f};
#pragma unroll
  for (int kk = 0; kk < 8; ++kk)
#pragma unroll
    for (int m = 0; m < 4; ++m)
#pragma unroll
      for (int g = 0; g < 3; ++g)
        pacc[m][g] = __builtin_amdgcn_mfma_f32_16x16x32_f16(areg[kk][m], bnt[g * 8 + kk], pacc[m][g], 0, 0, 0);
  // cross-wave K reduction (skip diagonal), lane-major conflict-free b32
#pragma unroll
  for (int m = 0; m < 4; ++m)
    if (m != wave)
#pragma unroll
      for (int g = 0; g < 3; ++g)
#pragma unroll
        for (int r = 0; r < 4; ++r)
          red[(((wave * 4 + m) * 3 + g) * 4 + r) * 64 + lane] = pacc[m][g][r];
  __syncthreads();
#pragma unroll
  for (int g = 0; g < 3; ++g) {
    f32x4 a = pacc[wave][g];
#pragma unroll
    for (int sw = 0; sw < 4; ++sw)
      if (sw != wave)
#pragma unroll
        for (int r = 0; r < 4; ++r)
          a[r] += red[(((sw * 4 + wave) * 3 + g) * 4 + r) * 64 + lane];
    acc[g] = a;
  }
}

__global__ __launch_bounds__(256, 1) void gru_main(
    const float* __restrict__ x, const float* __restrict__ xmask,
    const float* __restrict__ h0in,
    const float* __restrict__ Wih0, const float* __restrict__ Whh0,
    const float* __restrict__ bih0, const float* __restrict__ bhh0,
    const float* __restrict__ Wih1, const float* __restrict__ Whh1,
    const float* __restrict__ bih1, const float* __restrict__ bhh1,
    float* __restrict__ out, GruWS* __restrict__ ws) {
  __shared__ __align__(16) char ldsbuf[49152];   // 48KB: K-reduce scratch / store-stage tiles
  float* red = (float*)ldsbuf;

  const int bid = blockIdx.x;
  const int grp = bid >> 5;         // 0:L0gi 1:L0gh 2:L1gi 3:L1gh
  const int gidx = bid & 31;
  const int base = gidx * 32;       // 32 output columns per block
  const int tid = threadIdx.x;
  const int lane = tid & 63;
  const int wave = tid >> 6;
  const int l15 = lane & 15;
  const int kgrp = lane >> 4;
  const int b0 = wave * 16 + kgrp * 4;          // C-fragment batch base
  const int kbase0 = wave * 256 + kgrp * 8;     // this lane's K base
  unsigned* cnt = ws->cnt;

  // ---- stage W slice into registers: breg[nt][g][kk], cols base+nt*16+l15 ----
  const float* Wsrc = (grp == 0) ? Wih0 : (grp == 1) ? Whh0 : (grp == 2) ? Wih1 : Whh1;
  f16x8 breg[2][3][8];
#pragma unroll
  for (int nt = 0; nt < 2; ++nt)
#pragma unroll
    for (int g = 0; g < 3; ++g)
#pragma unroll
      for (int kk = 0; kk < 8; ++kk) {
        const float* p = Wsrc + (long)(g * HH + base + nt * 16 + l15) * DD + kbase0 + kk * 32;
        float4 v0 = *(const float4*)p;
        float4 v1 = *(const float4*)(p + 4);
        f16x8 t;
        t[0] = (f16)v0.x; t[1] = (f16)v0.y; t[2] = (f16)v0.z; t[3] = (f16)v0.w;
        t[4] = (f16)v1.x; t[5] = (f16)v1.y; t[6] = (f16)v1.z; t[7] = (f16)v1.w;
        breg[nt][g][kk] = t;
      }

  if (grp == 0 || grp == 2) {
    // ================= gi roles: gi = A @ Wih^T + (bih + bhh_{r,z}) =================
    const int layer = (grp == 2);
    const float* bih = layer ? bih1 : bih0;
    const float* bhh = layer ? bhh1 : bhh0;
    float bias[2][3];
#pragma unroll
    for (int nt = 0; nt < 2; ++nt)
#pragma unroll
      for (int g = 0; g < 3; ++g) {
        int colg = base + nt * 16 + l15;
        bias[nt][g] = bih[g * HH + colg] + (g < 2 ? bhh[g * HH + colg] : 0.0f);
      }

    for (int t = 0; t < TICKS; ++t) {
      const int s = t - (layer ? 2 : 0);
      const bool active = (s >= 0 && s < SS);
      if (active && tid < 2) {
        // parallel lane polling: lane0/1 each own one dependency
        int role, tk;
        if (!layer) { role = 1; tk = (tid == 0) ? t - 3 : -1; }      // gi0 slot free
        else        { role = (tid == 0) ? 1 : 3;                     // h0[s] ready / gi1 slot free
                      tk   = (tid == 0) ? t - 1 : t - 3; }
        wait_done(cnt, role, tk);
      }
      __syncthreads();  // S0
      if (active) {
        f16x8 areg[8][4];
        if (!layer) {
#pragma unroll
          for (int kk = 0; kk < 8; ++kk)
#pragma unroll
            for (int m = 0; m < 4; ++m) {
              const float* p = x + (long)(m * 16 + l15) * (SS * DD) + (long)s * DD + kbase0 + kk * 32;
              float4 v0 = *(const float4*)p;
              float4 v1 = *(const float4*)(p + 4);
              f16x8 a;
              a[0] = (f16)v0.x; a[1] = (f16)v0.y; a[2] = (f16)v0.z; a[3] = (f16)v0.w;
              a[4] = (f16)v1.x; a[5] = (f16)v1.y; a[6] = (f16)v1.z; a[7] = (f16)v1.w;
              areg[kk][m] = a;
            }
        } else {
          const f16* A = &ws->h0b[s & 3][0][0];
#pragma unroll
          for (int kk = 0; kk < 8; ++kk)
#pragma unroll
            for (int m = 0; m < 4; ++m)
              areg[kk][m] = ld_sys_16B(A + (long)(m * 16 + l15) * HH + kbase0 + kk * 32);
          drain_vm();
        }
        f32x4 accs[2][3];
        mma_pass(areg, &breg[0][0][0], red, lane, wave, accs[0]);
        __syncthreads();  // S2 (WAR on red)
        mma_pass(areg, &breg[1][0][0], red, lane, wave, accs[1]);
        __syncthreads();  // S4 (red dead -> tile alias)

        f16* gt = (f16*)ldsbuf;   // gi tile [96][64]
#pragma unroll
        for (int nt = 0; nt < 2; ++nt)
#pragma unroll
          for (int g = 0; g < 3; ++g) {
            f16x4 o;
#pragma unroll
            for (int r = 0; r < 4; ++r) o[r] = (f16)(accs[nt][g][r] + bias[nt][g]);
            *(f16x4*)(gt + (g * 32 + nt * 16 + l15) * 64 + b0) = o;
          }
        __syncthreads();  // S5
        f16* gib = layer ? &ws->gi1[s & 3][0][0] : &ws->gi0[s & 3][0][0];
#pragma unroll
        for (int rnd = 0; rnd < 3; ++rnd) {
          int idx = rnd * 256 + tid;
          int row = idx >> 3, ch = idx & 7;
          int g = row >> 5, c = row & 31;
          f16x8 v = *(const f16x8*)(gt + row * 64 + ch * 8);
          st_mall_16B(gib + (long)(g * HH + base + c) * BB + ch * 8, v);
        }
      }
      asm volatile("s_waitcnt vmcnt(0)" ::: "memory");
      __syncthreads();  // S6
      if (tid == 0)
        __hip_atomic_fetch_add(&cnt[(grp * 8 + (t & 7)) * 64], 1u,
                               __ATOMIC_RELAXED, __HIP_MEMORY_SCOPE_SYSTEM);
    }
  } else {
    // ================= gh roles: recurrent step =================
    const int layer = (grp == 3);
    const float* bhh = layer ? bhh1 : bhh0;
    float bhn[2], hold[2][4], osum[2][4];
#pragma unroll
    for (int nt = 0; nt < 2; ++nt) {
      bhn[nt] = bhh[2 * HH + base + nt * 16 + l15];
#pragma unroll
      for (int r = 0; r < 4; ++r) {
        hold[nt][r] = h0in[(long)layer * BB * HH + (long)(b0 + r) * HH + base + nt * 16 + l15];
        osum[nt][r] = 0.f;
      }
    }

    for (int t = 0; t < TICKS; ++t) {
      const int s = t - (layer ? 3 : 1);
      const bool active = (s >= 0 && s < SS);
      if (active && tid < 3) {
        int role, tk;
        if (!layer) {
          role = (tid == 0) ? 0 : (tid == 1) ? 1 : 2;   // gi0[s] ready / peers h0[s-1] / h0 slot free
          tk   = (tid == 2) ? t - 3 : t - 1;
        } else {
          role = (tid == 0) ? 2 : 3;                     // gi1[s] ready / peers h1[s-1]
          tk   = (tid < 2) ? t - 1 : -1;
        }
        wait_done(cnt, role, tk);
      }
      __syncthreads();  // S0
      if (active) {
        const f16* hprev = layer ? &ws->h1b[(s - 1) & 3][0][0] : &ws->h0b[(s - 1) & 3][0][0];
        const f16* gib = layer ? &ws->gi1[s & 3][0][0] : &ws->gi0[s & 3][0][0];
        f16x8 areg[8][4];
#pragma unroll
        for (int kk = 0; kk < 8; ++kk)
#pragma unroll
          for (int m = 0; m < 4; ++m)
            areg[kk][m] = ld_sys_16B(hprev + (long)(m * 16 + l15) * HH + kbase0 + kk * 32);
        f16x4 gfr[2][3];
#pragma unroll
        for (int nt = 0; nt < 2; ++nt)
#pragma unroll
          for (int g = 0; g < 3; ++g)
            gfr[nt][g] = ld_sys_f16x4(gib + (long)(g * HH + base + nt * 16 + l15) * BB + b0);
        float mv[4];
#pragma unroll
        for (int r = 0; r < 4; ++r) mv[r] = xmask[(long)(b0 + r) * SS + s];
        drain_vm();

        f32x4 accs[2][3];
        mma_pass(areg, &breg[0][0][0], red, lane, wave, accs[0]);
        __syncthreads();  // S2
        mma_pass(areg, &breg[1][0][0], red, lane, wave, accs[1]);
        __syncthreads();  // S4

        f16* htile = (f16*)ldsbuf;  // [64][32]
#pragma unroll
        for (int nt = 0; nt < 2; ++nt)
#pragma unroll
          for (int r = 0; r < 4; ++r) {
            float pr = accs[nt][0][r] + (float)gfr[nt][0][r];
            float pz = accs[nt][1][r] + (float)gfr[nt][1][r];
            float ph = accs[nt][2][r] + bhn[nt];
            float rr = 1.0f / (1.0f + __expf(-pr));
            float zz = 1.0f / (1.0f + __expf(-pz));
            float nn = tanhf((float)gfr[nt][2][r] + rr * ph);
            float upd = hold[nt][r] + (1.0f - zz) * (nn - hold[nt][r]);
            if (mv[r] > 0.5f) {
              hold[nt][r] = upd;
              if (layer) osum[nt][r] += upd;
            }
            htile[(b0 + r) * 32 + nt * 16 + l15] = (f16)hold[nt][r];
          }
        __syncthreads();  // S5
        f16* hout = layer ? &ws->h1b[s & 3][0][0] : &ws->h0b[s & 3][0][0];
        {
          int b = tid >> 2, ch = tid & 3;
          f16x8 v = *(const f16x8*)(htile + b * 32 + ch * 8);
          st_mall_16B(hout + (long)b * HH + base + ch * 8, v);
        }
        if (s == SS - 1 && layer) {
#pragma unroll
          for (int nt = 0; nt < 2; ++nt)
#pragma unroll
            for (int r = 0; r < 4; ++r) {
              int colg = base + nt * 16 + l15;
              float h0f = ld_sys_f16s(&ws->h0b[3][b0 + r][colg]);  // h0[511] lives in slot 3
              out[(long)(b0 + r) * HH + colg] =
                  (osum[nt][r] + hold[nt][r] + h0f) * (1.0f / 514.0f);
            }
        }
      }
      asm volatile("s_waitcnt vmcnt(0)" ::: "memory");
      __syncthreads();  // S6
      if (tid == 0)
        __hip_atomic_fetch_add(&cnt[(grp * 8 + (t & 7)) * 64], 1u,
                               __ATOMIC_RELAXED, __HIP_MEMORY_SCOPE_SYSTEM);
    }
  }
}

extern "C" void kernel_launch(void* const* d_in, const int* in_sizes, int n_in,
                              void* d_out, int out_size, void* d_ws, size_t ws_size,
                              hipStream_t stream) {
  const float* x = (const float*)d_in[0];
  const float* xmask = (const float*)d_in[1];
  const float* h0 = (const float*)d_in[2];
  const float* Wih0 = (const float*)d_in[3];
  const float* Whh0 = (const float*)d_in[4];
  const float* bih0 = (const float*)d_in[5];
  const float* bhh0 = (const float*)d_in[6];
  const float* Wih1 = (const float*)d_in[7];
  const float* Whh1 = (const float*)d_in[8];
  const float* bih1 = (const float*)d_in[9];
  const float* bhh1 = (const float*)d_in[10];
  float* out = (float*)d_out;
  GruWS* ws = (GruWS*)d_ws;

  hipLaunchKernelGGL(gru_init, dim3(128), dim3(256), 0, stream, h0, ws);
  hipLaunchKernelGGL(gru_main, dim3(NBLK), dim3(256), 0, stream,
                     x, xmask, h0, Wih0, Whh0, bih0, bhh0,
                     Wih1, Whh1, bih1, bhh1, out, ws);
}

// Round 7
// 9321.123 us; speedup vs baseline: 1.0838x; 1.0838x over previous
//
#include <hip/hip_runtime.h>
#include <hip/hip_fp16.h>

#define BB 64
#define SS 512
#define DD 1024
#define HH 1024
#define TICKS 515
#define NBLK 128

typedef _Float16 f16;
typedef unsigned long long u64;
typedef __attribute__((ext_vector_type(8))) _Float16 f16x8;
typedef __attribute__((ext_vector_type(4))) _Float16 f16x4;
typedef __attribute__((ext_vector_type(4))) float f32x4;

struct GruWS {
  unsigned sig[4 * 32 * 16];   // per-(role,member) signal word, one 64B line each; value = last completed tick + 1 (monotone)
  f16 gi0[4][3 * HH][BB];      // [slot][3H][B]
  f16 gi1[4][3 * HH][BB];
  f16 h0b[4][BB][HH];          // [slot][B][H], slot = s & 3
  f16 h1b[4][BB][HH];
};

// ---- MALL communication primitives ----
__device__ __forceinline__ f16x8 ld_sys_16B(const void* p) {
  f16x8 r;
  asm volatile("global_load_dwordx4 %0, %1, off sc0 sc1" : "=v"(r) : "v"(p) : "memory");
  return r;
}
__device__ __forceinline__ void st_sys_16B(void* p, f16x8 v) {
  asm volatile("global_store_dwordx4 %0, %1, off sc0 sc1" :: "v"(p), "v"(v) : "memory");
}
// h-state stores: atomic swaps execute at the MALL (keeps line hot for readers)
__device__ __forceinline__ void st_mall_16B(void* p, f16x8 v) {
  union { f16x8 v; u64 q[2]; } u; u.v = v;
  asm volatile("global_atomic_swap_x2 %0, %1, off sc1" :: "v"((u64*)p), "v"(u.q[0]) : "memory");
  asm volatile("global_atomic_swap_x2 %0, %1, off sc1" :: "v"((u64*)p + 1), "v"(u.q[1]) : "memory");
}
__device__ __forceinline__ void st_mall_8B(void* p, u64 q) {
  asm volatile("global_atomic_swap_x2 %0, %1, off sc1" :: "v"((u64*)p), "v"(q) : "memory");
}
// signal: no-return 4B swap (own cacheline per producer -> no RMW serialization)
__device__ __forceinline__ void sig_swap(unsigned* p, unsigned v) {
  asm volatile("global_atomic_swap %0, %1, off sc1" :: "v"(p), "v"(v) : "memory");
}
__device__ __forceinline__ void drain_vm() {
  asm volatile("s_waitcnt vmcnt(0)" ::: "memory");
  __builtin_amdgcn_sched_barrier(0);
}
__device__ __forceinline__ f16x4 ld_sys_f16x4(const f16* p) {
  u64 q = __hip_atomic_load((const u64*)p, __ATOMIC_RELAXED, __HIP_MEMORY_SCOPE_SYSTEM);
  union { u64 q; f16x4 v; } u; u.q = q; return u.v;
}
__device__ __forceinline__ float ld_sys_f16s(const f16* p) {
  unsigned short s = __hip_atomic_load((const unsigned short*)p, __ATOMIC_RELAXED, __HIP_MEMORY_SCOPE_SYSTEM);
  union { unsigned short s; f16 h; } u; u.s = s; return (float)u.h;
}

// wait until ALL 32 members of `role` have completed `tick`:
// one wave gathers the 32 per-member lines in parallel (lane i -> member i&31).
__device__ __forceinline__ void wait_all(const unsigned* sigrole, int tick, int lane) {
  if (tick < 0) return;
  const unsigned tgt = (unsigned)tick + 1u;
  const unsigned* p = sigrole + (lane & 31) * 16;
  for (;;) {
    unsigned v;
    asm volatile("global_load_dword %0, %1, off sc0 sc1" : "=v"(v) : "v"(p));
    asm volatile("s_waitcnt vmcnt(0)" ::: "memory");
    if (__all(v >= tgt)) break;
    __builtin_amdgcn_s_sleep(1);
  }
  asm volatile("" ::: "memory");
}

__global__ void gru_init(const float* __restrict__ h0, GruWS* __restrict__ ws) {
  int i = blockIdx.x * 256 + threadIdx.x;
  int j = i * 4;
  if (j < 2 * BB * HH) {
    union { f16 h[4]; u64 q; } u;
#pragma unroll
    for (int k = 0; k < 4; ++k) u.h[k] = (f16)h0[j + k];
    if (j < BB * HH) st_mall_8B(&ws->h0b[3][0][j], u.q);            // slot 3 == state of step -1
    else             st_mall_8B(&ws->h1b[3][0][j - BB * HH], u.q);
  }
  if (i < 4 * 32) {
    __hip_atomic_store(&ws->sig[i * 16], 0u, __ATOMIC_RELAXED, __HIP_MEMORY_SCOPE_SYSTEM);
  }
}

// One K-pass (this wave's K-quarter, one nt column-half): 96 MFMA + LDS K-reduce.
__device__ __forceinline__ void mma_pass(const f16x8 areg[8][4], const f16x8* bnt,
                                         float* red, int lane, int wave, f32x4 acc[3]) {
  f32x4 pacc[4][3];
#pragma unroll
  for (int m = 0; m < 4; ++m)
#pragma unroll
    for (int g = 0; g < 3; ++g) pacc[m][g] = (f32x4){0.f, 0.f, 0.f, 0.f};
#pragma unroll
  for (int kk = 0; kk < 8; ++kk)
#pragma unroll
    for (int m = 0; m < 4; ++m)
#pragma unroll
      for (int g = 0; g < 3; ++g)
        pacc[m][g] = __builtin_amdgcn_mfma_f32_16x16x32_f16(areg[kk][m], bnt[g * 8 + kk], pacc[m][g], 0, 0, 0);
  // cross-wave K reduction (skip diagonal), lane-major b32 (2-way bank alias = free)
#pragma unroll
  for (int m = 0; m < 4; ++m)
    if (m != wave)
#pragma unroll
      for (int g = 0; g < 3; ++g)
#pragma unroll
        for (int r = 0; r < 4; ++r)
          red[(((wave * 4 + m) * 3 + g) * 4 + r) * 64 + lane] = pacc[m][g][r];
  __syncthreads();
#pragma unroll
  for (int g = 0; g < 3; ++g) {
    f32x4 a = pacc[wave][g];
#pragma unroll
    for (int sw = 0; sw < 4; ++sw)
      if (sw != wave)
#pragma unroll
        for (int r = 0; r < 4; ++r)
          a[r] += red[(((sw * 4 + wave) * 3 + g) * 4 + r) * 64 + lane];
    acc[g] = a;
  }
}

__global__ __launch_bounds__(256, 1) void gru_main(
    const float* __restrict__ x, const float* __restrict__ xmask,
    const float* __restrict__ h0in,
    const float* __restrict__ Wih0, const float* __restrict__ Whh0,
    const float* __restrict__ bih0, const float* __restrict__ bhh0,
    const float* __restrict__ Wih1, const float* __restrict__ Whh1,
    const float* __restrict__ bih1, const float* __restrict__ bhh1,
    float* __restrict__ out, GruWS* __restrict__ ws) {
  __shared__ __align__(16) char ldsbuf[49152];   // 48KB: K-reduce scratch / store-stage tiles
  float* red = (float*)ldsbuf;

  const int bid = blockIdx.x;
  const int grp = bid >> 5;         // 0:L0gi 1:L0gh 2:L1gi 3:L1gh
  const int gidx = bid & 31;
  const int base = gidx * 32;       // 32 output columns per block
  const int tid = threadIdx.x;
  const int lane = tid & 63;
  const int wave = tid >> 6;
  const int l15 = lane & 15;
  const int kgrp = lane >> 4;
  const int b0 = wave * 16 + kgrp * 4;          // C-fragment batch base
  const int kbase0 = wave * 256 + kgrp * 8;     // this lane's K base
  unsigned* sig = ws->sig;
  unsigned* mysig = &sig[(grp * 32 + gidx) * 16];

  // ---- stage W slice into registers: breg[nt][g][kk], cols base+nt*16+l15 ----
  const float* Wsrc = (grp == 0) ? Wih0 : (grp == 1) ? Whh0 : (grp == 2) ? Wih1 : Whh1;
  f16x8 breg[2][3][8];
#pragma unroll
  for (int nt = 0; nt < 2; ++nt)
#pragma unroll
    for (int g = 0; g < 3; ++g)
#pragma unroll
      for (int kk = 0; kk < 8; ++kk) {
        const float* p = Wsrc + (long)(g * HH + base + nt * 16 + l15) * DD + kbase0 + kk * 32;
        float4 v0 = *(const float4*)p;
        float4 v1 = *(const float4*)(p + 4);
        f16x8 t;
        t[0] = (f16)v0.x; t[1] = (f16)v0.y; t[2] = (f16)v0.z; t[3] = (f16)v0.w;
        t[4] = (f16)v1.x; t[5] = (f16)v1.y; t[6] = (f16)v1.z; t[7] = (f16)v1.w;
        breg[nt][g][kk] = t;
      }

  if (grp == 0 || grp == 2) {
    // ================= gi roles: gi = A @ Wih^T + (bih + bhh_{r,z}) =================
    const int layer = (grp == 2);
    const float* bih = layer ? bih1 : bih0;
    const float* bhh = layer ? bhh1 : bhh0;
    float bias[2][3];
#pragma unroll
    for (int nt = 0; nt < 2; ++nt)
#pragma unroll
      for (int g = 0; g < 3; ++g) {
        int colg = base + nt * 16 + l15;
        bias[nt][g] = bih[g * HH + colg] + (g < 2 ? bhh[g * HH + colg] : 0.0f);
      }

    for (int t = 0; t < TICKS; ++t) {
      const int s = t - (layer ? 2 : 0);
      const bool active = (s >= 0 && s < SS);
      if (active) {
        // parallel dependency polls: one wave per dependency
        if (!layer) {
          if (wave == 0) wait_all(&sig[1 * 32 * 16], t - 3, lane);   // gi0 slot free
        } else {
          if (wave == 0) wait_all(&sig[1 * 32 * 16], t - 1, lane);   // h0[s] ready
          if (wave == 1) wait_all(&sig[3 * 32 * 16], t - 3, lane);   // gi1 slot free
        }
      }
      __syncthreads();  // S0
      if (active) {
        f16x8 areg[8][4];
        if (!layer) {
#pragma unroll
          for (int kk = 0; kk < 8; ++kk)
#pragma unroll
            for (int m = 0; m < 4; ++m) {
              const float* p = x + (long)(m * 16 + l15) * (SS * DD) + (long)s * DD + kbase0 + kk * 32;
              float4 v0 = *(const float4*)p;
              float4 v1 = *(const float4*)(p + 4);
              f16x8 a;
              a[0] = (f16)v0.x; a[1] = (f16)v0.y; a[2] = (f16)v0.z; a[3] = (f16)v0.w;
              a[4] = (f16)v1.x; a[5] = (f16)v1.y; a[6] = (f16)v1.z; a[7] = (f16)v1.w;
              areg[kk][m] = a;
            }
        } else {
          const f16* A = &ws->h0b[s & 3][0][0];
#pragma unroll
          for (int kk = 0; kk < 8; ++kk)
#pragma unroll
            for (int m = 0; m < 4; ++m)
              areg[kk][m] = ld_sys_16B(A + (long)(m * 16 + l15) * HH + kbase0 + kk * 32);
          drain_vm();
        }
        f32x4 accs[2][3];
        mma_pass(areg, &breg[0][0][0], red, lane, wave, accs[0]);
        __syncthreads();  // S2 (WAR on red)
        mma_pass(areg, &breg[1][0][0], red, lane, wave, accs[1]);
        __syncthreads();  // S4 (red dead -> tile alias)

        f16* gt = (f16*)ldsbuf;   // gi tile [96][64]
#pragma unroll
        for (int nt = 0; nt < 2; ++nt)
#pragma unroll
          for (int g = 0; g < 3; ++g) {
            f16x4 o;
#pragma unroll
            for (int r = 0; r < 4; ++r) o[r] = (f16)(accs[nt][g][r] + bias[nt][g]);
            *(f16x4*)(gt + (g * 32 + nt * 16 + l15) * 64 + b0) = o;
          }
        __syncthreads();  // S5
        f16* gib = layer ? &ws->gi1[s & 3][0][0] : &ws->gi0[s & 3][0][0];
#pragma unroll
        for (int rnd = 0; rnd < 3; ++rnd) {
          int idx = rnd * 256 + tid;
          int row = idx >> 3, ch = idx & 7;
          int g = row >> 5, c = row & 31;
          f16x8 v = *(const f16x8*)(gt + row * 64 + ch * 8);
          st_sys_16B(gib + (long)(g * HH + base + c) * BB + ch * 8, v);
        }
      }
      asm volatile("s_waitcnt vmcnt(0)" ::: "memory");
      __syncthreads();  // S6
      if (tid == 0) sig_swap(mysig, (unsigned)(t + 1));
    }
  } else {
    // ================= gh roles: recurrent step =================
    const int layer = (grp == 3);
    const float* bhh = layer ? bhh1 : bhh0;
    float bhn[2], hold[2][4], osum[2][4];
#pragma unroll
    for (int nt = 0; nt < 2; ++nt) {
      bhn[nt] = bhh[2 * HH + base + nt * 16 + l15];
#pragma unroll
      for (int r = 0; r < 4; ++r) {
        hold[nt][r] = h0in[(long)layer * BB * HH + (long)(b0 + r) * HH + base + nt * 16 + l15];
        osum[nt][r] = 0.f;
      }
    }

    for (int t = 0; t < TICKS; ++t) {
      const int s = t - (layer ? 3 : 1);
      const bool active = (s >= 0 && s < SS);
      if (active) {
        if (!layer) {
          if (wave == 0) wait_all(&sig[0 * 32 * 16], t - 1, lane);   // gi0[s] ready
          if (wave == 1) wait_all(&sig[1 * 32 * 16], t - 1, lane);   // peers' h0[s-1] ready
          if (wave == 2) wait_all(&sig[2 * 32 * 16], t - 3, lane);   // h0 slot free (L1gi consumed)
        } else {
          if (wave == 0) wait_all(&sig[2 * 32 * 16], t - 1, lane);   // gi1[s] ready
          if (wave == 1) wait_all(&sig[3 * 32 * 16], t - 1, lane);   // peers' h1[s-1] ready
        }
      }
      __syncthreads();  // S0
      if (active) {
        const f16* hprev = layer ? &ws->h1b[(s - 1) & 3][0][0] : &ws->h0b[(s - 1) & 3][0][0];
        const f16* gib = layer ? &ws->gi1[s & 3][0][0] : &ws->gi0[s & 3][0][0];
        f16x8 areg[8][4];
#pragma unroll
        for (int kk = 0; kk < 8; ++kk)
#pragma unroll
          for (int m = 0; m < 4; ++m)
            areg[kk][m] = ld_sys_16B(hprev + (long)(m * 16 + l15) * HH + kbase0 + kk * 32);
        f16x4 gfr[2][3];
#pragma unroll
        for (int nt = 0; nt < 2; ++nt)
#pragma unroll
          for (int g = 0; g < 3; ++g)
            gfr[nt][g] = ld_sys_f16x4(gib + (long)(g * HH + base + nt * 16 + l15) * BB + b0);
        float mv[4];
#pragma unroll
        for (int r = 0; r < 4; ++r) mv[r] = xmask[(long)(b0 + r) * SS + s];
        drain_vm();

        f32x4 accs[2][3];
        mma_pass(areg, &breg[0][0][0], red, lane, wave, accs[0]);
        __syncthreads();  // S2
        mma_pass(areg, &breg[1][0][0], red, lane, wave, accs[1]);
        __syncthreads();  // S4

        f16* htile = (f16*)ldsbuf;  // [64][32]
#pragma unroll
        for (int nt = 0; nt < 2; ++nt)
#pragma unroll
          for (int r = 0; r < 4; ++r) {
            float pr = accs[nt][0][r] + (float)gfr[nt][0][r];
            float pz = accs[nt][1][r] + (float)gfr[nt][1][r];
            float ph = accs[nt][2][r] + bhn[nt];
            float rr = 1.0f / (1.0f + __expf(-pr));
            float zz = 1.0f / (1.0f + __expf(-pz));
            float nn = tanhf((float)gfr[nt][2][r] + rr * ph);
            float upd = hold[nt][r] + (1.0f - zz) * (nn - hold[nt][r]);
            if (mv[r] > 0.5f) {
              hold[nt][r] = upd;
              if (layer) osum[nt][r] += upd;
            }
            htile[(b0 + r) * 32 + nt * 16 + l15] = (f16)hold[nt][r];
          }
        __syncthreads();  // S5
        f16* hout = layer ? &ws->h1b[s & 3][0][0] : &ws->h0b[s & 3][0][0];
        {
          int b = tid >> 2, ch = tid & 3;
          f16x8 v = *(const f16x8*)(htile + b * 32 + ch * 8);
          st_mall_16B(hout + (long)b * HH + base + ch * 8, v);
        }
        if (s == SS - 1 && layer) {
#pragma unroll
          for (int nt = 0; nt < 2; ++nt)
#pragma unroll
            for (int r = 0; r < 4; ++r) {
              int colg = base + nt * 16 + l15;
              float h0f = ld_sys_f16s(&ws->h0b[3][b0 + r][colg]);  // h0[511] lives in slot 3
              out[(long)(b0 + r) * HH + colg] =
                  (osum[nt][r] + hold[nt][r] + h0f) * (1.0f / 514.0f);
            }
        }
      }
      asm volatile("s_waitcnt vmcnt(0)" ::: "memory");
      __syncthreads();  // S6
      if (tid == 0) sig_swap(mysig, (unsigned)(t + 1));
    }
  }
}

extern "C" void kernel_launch(void* const* d_in, const int* in_sizes, int n_in,
                              void* d_out, int out_size, void* d_ws, size_t ws_size,
                              hipStream_t stream) {
  const float* x = (const float*)d_in[0];
  const float* xmask = (const float*)d_in[1];
  const float* h0 = (const float*)d_in[2];
  const float* Wih0 = (const float*)d_in[3];
  const float* Whh0 = (const float*)d_in[4];
  const float* bih0 = (const float*)d_in[5];
  const float* bhh0 = (const float*)d_in[6];
  const float* Wih1 = (const float*)d_in[7];
  const float* Whh1 = (const float*)d_in[8];
  const float* bih1 = (const float*)d_in[9];
  const float* bhh1 = (const float*)d_in[10];
  float* out = (float*)d_out;
  GruWS* ws = (GruWS*)d_ws;

  hipLaunchKernelGGL(gru_init, dim3(128), dim3(256), 0, stream, h0, ws);
  hipLaunchKernelGGL(gru_main, dim3(NBLK), dim3(256), 0, stream,
                     x, xmask, h0, Wih0, Whh0, bih0, bhh0,
                     Wih1, Whh1, bih1, bhh1, out, ws);
}